// Round 1
// baseline (326.782 us; speedup 1.0000x reference)
//
#include <hip/hip_runtime.h>
#include <math.h>

#define H_ 192
#define W_ 192
#define HW_ 36864
#define C_ 64
#define O_ 64
#define B_ 2
#define K_ 9
#define EPS_ 1e-5f

// ---------------- K1: depthwise 3x3 conv + bias + BN + ReLU -> h ----------------
__global__ __launch_bounds__(256) void k1_dw(const float* __restrict__ x,
                                             const float* __restrict__ dw_w,
                                             const float* __restrict__ dw_b,
                                             const float* __restrict__ bn_g,
                                             const float* __restrict__ bn_b,
                                             const float* __restrict__ bn_m,
                                             const float* __restrict__ bn_v,
                                             float* __restrict__ h) {
  const int plane = blockIdx.y;                 // b*C + c
  const int c = plane & (C_ - 1);
  const int p = blockIdx.x * 256 + threadIdx.x; // pixel in plane
  const int y = p / W_;
  const int xx = p - y * W_;
  const float* xp = x + (size_t)plane * HW_;
  float w[9];
#pragma unroll
  for (int i = 0; i < 9; ++i) w[i] = dw_w[c * 9 + i];
  float s = 0.f;
#pragma unroll
  for (int dy = 0; dy < 3; ++dy) {
    const int yy = y + dy - 1;
    if (yy < 0 || yy >= H_) continue;
#pragma unroll
    for (int dx = 0; dx < 3; ++dx) {
      const int xc = xx + dx - 1;
      if (xc < 0 || xc >= W_) continue;
      s = fmaf(w[dy * 3 + dx], xp[yy * W_ + xc], s);
    }
  }
  const float scale = bn_g[c] * rsqrtf(bn_v[c] + EPS_);
  const float shift = fmaf(dw_b[c] - bn_m[c], scale, bn_b[c]);
  h[(size_t)plane * HW_ + p] = fmaxf(fmaf(s, scale, shift), 0.f);
}

// ---------------- K2: pointwise 64->27 per pixel -> om ----------------
__global__ __launch_bounds__(256) void k2_pw(const float* __restrict__ h,
                                             const float* __restrict__ pw_w,
                                             const float* __restrict__ pw_b,
                                             float* __restrict__ om) {
  __shared__ float wl[C_ * 28];  // [c][j] padded to 28 for float4 reads
  const int b = blockIdx.y;
  const int p = blockIdx.x * 256 + threadIdx.x;
  for (int i = threadIdx.x; i < C_ * 28; i += 256) {
    const int c = i / 28, j = i - c * 28;
    wl[i] = (j < 27) ? pw_w[j * C_ + c] : 0.f;
  }
  __syncthreads();
  float s[27];
#pragma unroll
  for (int j = 0; j < 27; ++j) s[j] = 0.f;
  const float* hp = h + (size_t)b * C_ * HW_ + p;
  for (int c = 0; c < C_; ++c) {
    const float hv = hp[(size_t)c * HW_];
    float wv[28];
#pragma unroll
    for (int q = 0; q < 7; ++q)
      *(float4*)&wv[q * 4] = *(const float4*)&wl[c * 28 + q * 4];
#pragma unroll
    for (int j = 0; j < 27; ++j) s[j] = fmaf(hv, wv[j], s[j]);
  }
  float* op = om + (size_t)b * 27 * HW_ + p;
#pragma unroll
  for (int j = 0; j < 27; ++j) op[(size_t)j * HW_] = s[j] + pw_b[j];
}

// ---------------- K0: transpose dcn_w (O,C,3,3) -> wT[k][c][o] ----------------
__global__ __launch_bounds__(256) void k0_wt(const float* __restrict__ dcn_w,
                                             float* __restrict__ wT) {
  const int i = blockIdx.x * 256 + threadIdx.x;  // (o*C + c)*9 + k
  const int o = i / (C_ * 9);
  const int rem = i - o * (C_ * 9);
  const int c = rem / 9;
  const int k = rem - c * 9;
  wT[((size_t)(k * C_) + c) * O_ + o] = dcn_w[i];
}

// ---------------- K3: fused deformable gather + 64x576 contraction ----------------
// block: 256 threads = 8 (o-groups of 8) x 32 (px-groups of 4); 128 px, all 64 o.
__global__ __launch_bounds__(256) void k3_dcn(const float* __restrict__ x,
                                              const float* __restrict__ om,
                                              const float* __restrict__ wT,
                                              float* __restrict__ pre) {
  __shared__ float wlds[C_ * O_];   // [c][o]    16 KB
  __shared__ float vlds[C_][128];   // [c][px]   32 KB
  __shared__ int offs[128][4];      //            2 KB
  __shared__ float wts[128][4];     //            2 KB

  const int tid = threadIdx.x;
  const int pg0 = blockIdx.x * 128;
  const int b = pg0 / HW_;
  const int p0 = pg0 - b * HW_;
  const float* xb = x + (size_t)b * C_ * HW_;
  const float* omb = om + (size_t)b * 27 * HW_;

  const int to = tid >> 5;  // 0..7 -> o = to*8..to*8+7
  const int tp = tid & 31;  // 0..31 -> px = tp*4..tp*4+3

  float acc[8][4];
#pragma unroll
  for (int i = 0; i < 8; ++i)
#pragma unroll
    for (int j = 0; j < 4; ++j) acc[i][j] = 0.f;

  for (int k = 0; k < K_; ++k) {
    __syncthreads();  // (A) previous iteration done reading LDS
    // stage weights for this tap (coalesced from wT)
    {
      const float4* src = (const float4*)(wT + (size_t)k * C_ * O_);
#pragma unroll
      for (int q = 0; q < 4; ++q)
        ((float4*)wlds)[q * 256 + tid] = src[q * 256 + tid];
    }
    // bilinear coords for the 128 pixels (waves 0-1 only; wave-uniform branch)
    if (tid < 128) {
      const int p = p0 + tid;
      const int y = p / W_;
      const int xx = p - y * W_;
      const float dyv = omb[(size_t)(2 * k) * HW_ + p];
      const float dxv = omb[(size_t)(2 * k + 1) * HW_ + p];
      float mk = omb[(size_t)(18 + k) * HW_ + p];
      mk = 1.f / (1.f + __expf(-mk));
      const float py = (float)(y + (k / 3) - 1) + dyv;
      const float px = (float)(xx + (k % 3) - 1) + dxv;
      const float y0f = floorf(py), x0f = floorf(px);
      const float wy1 = py - y0f, wx1 = px - x0f;
      const float wy0 = 1.f - wy1, wx0 = 1.f - wx1;
      const int y0 = (int)y0f, x0i = (int)x0f;
      const int y1 = y0 + 1, x1i = x0i + 1;
      const bool vy0 = (y0 >= 0) & (y0 < H_);
      const bool vy1 = (y1 >= 0) & (y1 < H_);
      const bool vx0 = (x0i >= 0) & (x0i < W_);
      const bool vx1 = (x1i >= 0) & (x1i < W_);
      const int yc0 = min(max(y0, 0), H_ - 1), yc1 = min(max(y1, 0), H_ - 1);
      const int xc0 = min(max(x0i, 0), W_ - 1), xc1 = min(max(x1i, 0), W_ - 1);
      offs[tid][0] = yc0 * W_ + xc0;
      offs[tid][1] = yc0 * W_ + xc1;
      offs[tid][2] = yc1 * W_ + xc0;
      offs[tid][3] = yc1 * W_ + xc1;
      wts[tid][0] = (vy0 & vx0) ? wy0 * wx0 * mk : 0.f;
      wts[tid][1] = (vy0 & vx1) ? wy0 * wx1 * mk : 0.f;
      wts[tid][2] = (vy1 & vx0) ? wy1 * wx0 * mk : 0.f;
      wts[tid][3] = (vy1 & vx1) ? wy1 * wx1 * mk : 0.f;
    }
    __syncthreads();  // (B) weights + coords ready
    // gather: each thread fills 32 (c,px) entries of vlds
    {
      const int pxi = tid & 127;
      const int chalf = tid >> 7;
      const int4 o4 = *(const int4*)offs[pxi];
      const float4 w4 = *(const float4*)wts[pxi];
#pragma unroll
      for (int i = 0; i < 32; ++i) {
        const int c = (i << 1) + chalf;
        const float* pl = xb + (size_t)c * HW_;
        const float v = fmaf(w4.x, pl[o4.x],
                        fmaf(w4.y, pl[o4.y],
                        fmaf(w4.z, pl[o4.z], w4.w * pl[o4.w])));
        vlds[c][pxi] = v;
      }
    }
    __syncthreads();  // (C) vlds ready
    // register-tiled GEMM: acc[8][4] += w[c][8o] * val[c][4px]
    for (int c = 0; c < C_; ++c) {
      const float4 v4 = *(const float4*)&vlds[c][tp << 2];
      const float4 wa = *(const float4*)&wlds[(c << 6) + (to << 3)];
      const float4 wb = *(const float4*)&wlds[(c << 6) + (to << 3) + 4];
      const float wv[8] = {wa.x, wa.y, wa.z, wa.w, wb.x, wb.y, wb.z, wb.w};
      const float vv[4] = {v4.x, v4.y, v4.z, v4.w};
#pragma unroll
      for (int i = 0; i < 8; ++i)
#pragma unroll
        for (int j = 0; j < 4; ++j) acc[i][j] = fmaf(wv[i], vv[j], acc[i][j]);
    }
  }
  // write pre-norm output (dcn_b omitted: cancels in instance norm)
#pragma unroll
  for (int i = 0; i < 8; ++i) {
    const int o = (to << 3) + i;
    float4 v;
    v.x = acc[i][0]; v.y = acc[i][1]; v.z = acc[i][2]; v.w = acc[i][3];
    *(float4*)&pre[((size_t)b * O_ + o) * HW_ + p0 + (tp << 2)] = v;
  }
}

// ---------------- K4: instance-norm stats (two-pass, deterministic) ----------------
__global__ __launch_bounds__(512) void k4_part(const float* __restrict__ pre,
                                               float* __restrict__ pstats) {
  const int plane = blockIdx.x >> 1;
  const int half = blockIdx.x & 1;
  const float4* p4 = (const float4*)(pre + (size_t)plane * HW_) + half * 4608;
  float s = 0.f, s2 = 0.f;
#pragma unroll
  for (int q = 0; q < 9; ++q) {
    const float4 v = p4[q * 512 + threadIdx.x];
    s += v.x + v.y + v.z + v.w;
    s2 = fmaf(v.x, v.x, s2);
    s2 = fmaf(v.y, v.y, s2);
    s2 = fmaf(v.z, v.z, s2);
    s2 = fmaf(v.w, v.w, s2);
  }
#pragma unroll
  for (int off = 32; off > 0; off >>= 1) {
    s += __shfl_down(s, off);
    s2 += __shfl_down(s2, off);
  }
  __shared__ float ls[8], ls2[8];
  const int wid = threadIdx.x >> 6, lane = threadIdx.x & 63;
  if (lane == 0) { ls[wid] = s; ls2[wid] = s2; }
  __syncthreads();
  if (threadIdx.x == 0) {
    float ts = 0.f, ts2 = 0.f;
#pragma unroll
    for (int w = 0; w < 8; ++w) { ts += ls[w]; ts2 += ls2[w]; }
    pstats[blockIdx.x * 2] = ts;
    pstats[blockIdx.x * 2 + 1] = ts2;
  }
}

__global__ void k4_fin(const float* __restrict__ pstats, float* __restrict__ stats) {
  const int p = threadIdx.x;  // 0..127 = b*O + o
  const float s = pstats[(2 * p) * 2] + pstats[(2 * p + 1) * 2];
  const float s2 = pstats[(2 * p) * 2 + 1] + pstats[(2 * p + 1) * 2 + 1];
  const float inv = 1.f / (float)HW_;
  const float mu = s * inv;
  const float var = fmaxf(fmaf(-mu, mu, s2 * inv), 0.f);
  stats[p * 2] = mu;
  stats[p * 2 + 1] = rsqrtf(var + EPS_);
}

// ---------------- K5: apply instance norm + ReLU ----------------
__global__ __launch_bounds__(256) void k5_norm(const float* __restrict__ pre,
                                               const float* __restrict__ stats,
                                               float* __restrict__ out) {
  const int i4 = blockIdx.x * 256 + threadIdx.x;
  const int plane = i4 / 9216;  // HW_/4 float4 per plane
  const float mu = stats[plane * 2];
  const float rs = stats[plane * 2 + 1];
  float4 v = ((const float4*)pre)[i4];
  v.x = fmaxf((v.x - mu) * rs, 0.f);
  v.y = fmaxf((v.y - mu) * rs, 0.f);
  v.z = fmaxf((v.z - mu) * rs, 0.f);
  v.w = fmaxf((v.w - mu) * rs, 0.f);
  ((float4*)out)[i4] = v;
}

extern "C" void kernel_launch(void* const* d_in, const int* in_sizes, int n_in,
                              void* d_out, int out_size, void* d_ws, size_t ws_size,
                              hipStream_t stream) {
  const float* x = (const float*)d_in[0];
  const float* dw_w = (const float*)d_in[1];
  const float* dw_b = (const float*)d_in[2];
  const float* bn_g = (const float*)d_in[3];
  const float* bn_b = (const float*)d_in[4];
  const float* bn_m = (const float*)d_in[5];
  const float* bn_v = (const float*)d_in[6];
  const float* pw_w = (const float*)d_in[7];
  const float* pw_b = (const float*)d_in[8];
  const float* dcn_w = (const float*)d_in[9];
  float* out = (float*)d_out;

  // workspace layout (floats)
  float* ws = (float*)d_ws;
  float* h = ws;                                  // B*C*HW = 4718592 (reused as pre)
  float* om = h + (size_t)B_ * C_ * HW_;          // B*27*HW = 1990656
  float* wT = om + (size_t)B_ * 27 * HW_;         // 9*64*64 = 36864
  float* pstats = wT + (size_t)K_ * C_ * O_;      // 512
  float* stats = pstats + 512;                    // 256
  if (ws_size < (size_t)(4718592 + 1990656 + 36864 + 512 + 256) * sizeof(float)) return;
  float* pre = h;  // h is dead after k2; reuse for pre-norm output

  k0_wt<<<dim3(144), dim3(256), 0, stream>>>(dcn_w, wT);
  k1_dw<<<dim3(HW_ / 256, B_ * C_), dim3(256), 0, stream>>>(x, dw_w, dw_b, bn_g, bn_b,
                                                            bn_m, bn_v, h);
  k2_pw<<<dim3(HW_ / 256, B_), dim3(256), 0, stream>>>(h, pw_w, pw_b, om);
  k3_dcn<<<dim3(B_ * HW_ / 128), dim3(256), 0, stream>>>(x, om, wT, pre);
  k4_part<<<dim3(B_ * O_ * 2), dim3(512), 0, stream>>>(pre, pstats);
  k4_fin<<<dim3(1), dim3(128), 0, stream>>>(pstats, stats);
  k5_norm<<<dim3(B_ * O_ * HW_ / 4 / 256), dim3(256), 0, stream>>>(pre, stats, out);
}

// Round 2
// 226.991 us; speedup vs baseline: 1.4396x; 1.4396x over previous
//
#include <hip/hip_runtime.h>
#include <math.h>

#define H_ 192
#define W_ 192
#define HW_ 36864
#define C_ 64
#define O_ 64
#define B_ 2
#define K_ 9
#define EPS_ 1e-5f

// ---------------- K1: depthwise 3x3 conv + bias + BN + ReLU -> h ----------------
__global__ __launch_bounds__(256) void k1_dw(const float* __restrict__ x,
                                             const float* __restrict__ dw_w,
                                             const float* __restrict__ dw_b,
                                             const float* __restrict__ bn_g,
                                             const float* __restrict__ bn_b,
                                             const float* __restrict__ bn_m,
                                             const float* __restrict__ bn_v,
                                             float* __restrict__ h) {
  const int plane = blockIdx.y;                 // b*C + c
  const int c = plane & (C_ - 1);
  const int p = blockIdx.x * 256 + threadIdx.x; // pixel in plane
  const int y = p / W_;
  const int xx = p - y * W_;
  const float* xp = x + (size_t)plane * HW_;
  float w[9];
#pragma unroll
  for (int i = 0; i < 9; ++i) w[i] = dw_w[c * 9 + i];
  float s = 0.f;
#pragma unroll
  for (int dy = 0; dy < 3; ++dy) {
    const int yy = y + dy - 1;
    if (yy < 0 || yy >= H_) continue;
#pragma unroll
    for (int dx = 0; dx < 3; ++dx) {
      const int xc = xx + dx - 1;
      if (xc < 0 || xc >= W_) continue;
      s = fmaf(w[dy * 3 + dx], xp[yy * W_ + xc], s);
    }
  }
  const float scale = bn_g[c] * rsqrtf(bn_v[c] + EPS_);
  const float shift = fmaf(dw_b[c] - bn_m[c], scale, bn_b[c]);
  h[(size_t)plane * HW_ + p] = fmaxf(fmaf(s, scale, shift), 0.f);
}

// ---------------- K2: pointwise 64->27 per pixel -> om ----------------
__global__ __launch_bounds__(256) void k2_pw(const float* __restrict__ h,
                                             const float* __restrict__ pw_w,
                                             const float* __restrict__ pw_b,
                                             float* __restrict__ om) {
  __shared__ float wl[C_ * 28];  // [c][j] padded to 28 for float4 reads
  const int b = blockIdx.y;
  const int p = blockIdx.x * 256 + threadIdx.x;
  for (int i = threadIdx.x; i < C_ * 28; i += 256) {
    const int c = i / 28, j = i - c * 28;
    wl[i] = (j < 27) ? pw_w[j * C_ + c] : 0.f;
  }
  __syncthreads();
  float s[27];
#pragma unroll
  for (int j = 0; j < 27; ++j) s[j] = 0.f;
  const float* hp = h + (size_t)b * C_ * HW_ + p;
  for (int c = 0; c < C_; ++c) {
    const float hv = hp[(size_t)c * HW_];
    float wv[28];
#pragma unroll
    for (int q = 0; q < 7; ++q)
      *(float4*)&wv[q * 4] = *(const float4*)&wl[c * 28 + q * 4];
#pragma unroll
    for (int j = 0; j < 27; ++j) s[j] = fmaf(hv, wv[j], s[j]);
  }
  float* op = om + (size_t)b * 27 * HW_ + p;
#pragma unroll
  for (int j = 0; j < 27; ++j) op[(size_t)j * HW_] = s[j] + pw_b[j];
}

// ---------------- K0: transpose dcn_w (O,C,3,3) -> wT[k][c][o] ----------------
__global__ __launch_bounds__(256) void k0_wt(const float* __restrict__ dcn_w,
                                             float* __restrict__ wT) {
  const int i = blockIdx.x * 256 + threadIdx.x;  // (o*C + c)*9 + k
  const int o = i / (C_ * 9);
  const int rem = i - o * (C_ * 9);
  const int c = rem / 9;
  const int k = rem - c * 9;
  wT[((size_t)(k * C_) + c) * O_ + o] = dcn_w[i];
}

// ---------------- K3: fused deformable gather + 64x576 contraction ----------------
// 64-px tile, 64 o, 256 threads. thread GEMM tile = 4o x 4px.
// XCD-swizzled block order: each XCD owns a contiguous quarter-image -> x gather L2-resident.
__global__ __launch_bounds__(256, 4) void k3_dcn(const float* __restrict__ x,
                                                 const float* __restrict__ om,
                                                 const float* __restrict__ wT,
                                                 float* __restrict__ pre) {
  __shared__ float wlds[C_ * O_];  // [c][o] 16 KB, restaged per tap
  __shared__ float vlds[C_][64];   // [c][px] 16 KB

  const int tid = threadIdx.x;
  // bijective XCD swizzle: 1152 blocks = 8 XCD x 144 contiguous tiles
  const int t = (blockIdx.x & 7) * 144 + (blockIdx.x >> 3);
  const int b = t / 576;
  const int p0 = (t - b * 576) * 64;
  const float* xb = x + (size_t)b * C_ * HW_;
  const float* omb = om + (size_t)b * 27 * HW_;

  const int to = tid >> 4;  // 0..15 -> o = to*4
  const int tp = tid & 15;  // 0..15 -> px = tp*4
  const int pxi = tid & 63; // gather pixel (4 threads per px)
  const int chalf = tid >> 6;  // 0..3
  const int p = p0 + pxi;
  const int y = p / W_;
  const int xx = p - y * W_;

  float acc[4][4];
#pragma unroll
  for (int i = 0; i < 4; ++i)
#pragma unroll
    for (int j = 0; j < 4; ++j) acc[i][j] = 0.f;

  for (int k = 0; k < K_; ++k) {
    // --- per-thread bilinear coords (redundant x4 per px; no LDS, no divergence)
    const float dyv = omb[(size_t)(2 * k) * HW_ + p];
    const float dxv = omb[(size_t)(2 * k + 1) * HW_ + p];
    float mk = omb[(size_t)(18 + k) * HW_ + p];
    mk = 1.f / (1.f + __expf(-mk));
    const float py = (float)(y + (k / 3) - 1) + dyv;
    const float pxf = (float)(xx + (k % 3) - 1) + dxv;
    const float y0f = floorf(py), x0f = floorf(pxf);
    const float wy1 = py - y0f, wx1 = pxf - x0f;
    const float wy0 = 1.f - wy1, wx0 = 1.f - wx1;
    const int y0 = (int)y0f, x0i = (int)x0f;
    const int y1 = y0 + 1, x1i = x0i + 1;
    const bool vy0 = (y0 >= 0) & (y0 < H_);
    const bool vy1 = (y1 >= 0) & (y1 < H_);
    const bool vx0 = (x0i >= 0) & (x0i < W_);
    const bool vx1 = (x1i >= 0) & (x1i < W_);
    const int yc0 = min(max(y0, 0), H_ - 1), yc1 = min(max(y1, 0), H_ - 1);
    const int xc0 = min(max(x0i, 0), W_ - 1), xc1 = min(max(x1i, 0), W_ - 1);
    const int o0 = yc0 * W_ + xc0, o1 = yc0 * W_ + xc1;
    const int o2 = yc1 * W_ + xc0, o3 = yc1 * W_ + xc1;
    const float g0 = (vy0 & vx0) ? wy0 * wx0 * mk : 0.f;
    const float g1 = (vy0 & vx1) ? wy0 * wx1 * mk : 0.f;
    const float g2 = (vy1 & vx0) ? wy1 * wx0 * mk : 0.f;
    const float g3 = (vy1 & vx1) ? wy1 * wx1 * mk : 0.f;

    __syncthreads();  // (A) previous tap's GEMM done reading wlds/vlds
    // --- stage weights for this tap (coalesced; 4 float4 per thread)
    {
      const float4* srcw = (const float4*)(wT + (size_t)k * C_ * O_);
      ((float4*)wlds)[tid] = srcw[tid];
      ((float4*)wlds)[256 + tid] = srcw[256 + tid];
      ((float4*)wlds)[512 + tid] = srcw[512 + tid];
      ((float4*)wlds)[768 + tid] = srcw[768 + tid];
    }
    // --- gather: 16 (c,px) values per thread; contiguous-row LDS writes
#pragma unroll
    for (int i = 0; i < 16; ++i) {
      const int c = (i << 2) + chalf;
      const float* pl = xb + (size_t)c * HW_;
      vlds[c][pxi] = fmaf(g0, pl[o0],
                     fmaf(g1, pl[o1],
                     fmaf(g2, pl[o2], g3 * pl[o3])));
    }
    __syncthreads();  // (B) vlds + wlds ready
    // --- register-tiled GEMM: acc[4o][4px] += w[c][4o] * val[c][4px]
#pragma unroll 4
    for (int c = 0; c < C_; ++c) {
      const float4 v4 = *(const float4*)&vlds[c][tp << 2];
      const float4 w4 = *(const float4*)&wlds[(c << 6) + (to << 2)];
      acc[0][0] = fmaf(w4.x, v4.x, acc[0][0]);
      acc[0][1] = fmaf(w4.x, v4.y, acc[0][1]);
      acc[0][2] = fmaf(w4.x, v4.z, acc[0][2]);
      acc[0][3] = fmaf(w4.x, v4.w, acc[0][3]);
      acc[1][0] = fmaf(w4.y, v4.x, acc[1][0]);
      acc[1][1] = fmaf(w4.y, v4.y, acc[1][1]);
      acc[1][2] = fmaf(w4.y, v4.z, acc[1][2]);
      acc[1][3] = fmaf(w4.y, v4.w, acc[1][3]);
      acc[2][0] = fmaf(w4.z, v4.x, acc[2][0]);
      acc[2][1] = fmaf(w4.z, v4.y, acc[2][1]);
      acc[2][2] = fmaf(w4.z, v4.z, acc[2][2]);
      acc[2][3] = fmaf(w4.z, v4.w, acc[2][3]);
      acc[3][0] = fmaf(w4.w, v4.x, acc[3][0]);
      acc[3][1] = fmaf(w4.w, v4.y, acc[3][1]);
      acc[3][2] = fmaf(w4.w, v4.z, acc[3][2]);
      acc[3][3] = fmaf(w4.w, v4.w, acc[3][3]);
    }
  }
  // write pre-norm output (dcn_b omitted: cancels in instance norm)
#pragma unroll
  for (int i = 0; i < 4; ++i) {
    const int o = (to << 2) + i;
    float4 v;
    v.x = acc[i][0]; v.y = acc[i][1]; v.z = acc[i][2]; v.w = acc[i][3];
    *(float4*)&pre[((size_t)b * O_ + o) * HW_ + p0 + (tp << 2)] = v;
  }
}

// ---------------- K4: instance-norm stats (two-pass, deterministic) ----------------
__global__ __launch_bounds__(512) void k4_part(const float* __restrict__ pre,
                                               float* __restrict__ pstats) {
  const int plane = blockIdx.x >> 1;
  const int half = blockIdx.x & 1;
  const float4* p4 = (const float4*)(pre + (size_t)plane * HW_) + half * 4608;
  float s = 0.f, s2 = 0.f;
#pragma unroll
  for (int q = 0; q < 9; ++q) {
    const float4 v = p4[q * 512 + threadIdx.x];
    s += v.x + v.y + v.z + v.w;
    s2 = fmaf(v.x, v.x, s2);
    s2 = fmaf(v.y, v.y, s2);
    s2 = fmaf(v.z, v.z, s2);
    s2 = fmaf(v.w, v.w, s2);
  }
#pragma unroll
  for (int off = 32; off > 0; off >>= 1) {
    s += __shfl_down(s, off);
    s2 += __shfl_down(s2, off);
  }
  __shared__ float ls[8], ls2[8];
  const int wid = threadIdx.x >> 6, lane = threadIdx.x & 63;
  if (lane == 0) { ls[wid] = s; ls2[wid] = s2; }
  __syncthreads();
  if (threadIdx.x == 0) {
    float ts = 0.f, ts2 = 0.f;
#pragma unroll
    for (int w = 0; w < 8; ++w) { ts += ls[w]; ts2 += ls2[w]; }
    pstats[blockIdx.x * 2] = ts;
    pstats[blockIdx.x * 2 + 1] = ts2;
  }
}

__global__ void k4_fin(const float* __restrict__ pstats, float* __restrict__ stats) {
  const int p = threadIdx.x;  // 0..127 = b*O + o
  const float s = pstats[(2 * p) * 2] + pstats[(2 * p + 1) * 2];
  const float s2 = pstats[(2 * p) * 2 + 1] + pstats[(2 * p + 1) * 2 + 1];
  const float inv = 1.f / (float)HW_;
  const float mu = s * inv;
  const float var = fmaxf(fmaf(-mu, mu, s2 * inv), 0.f);
  stats[p * 2] = mu;
  stats[p * 2 + 1] = rsqrtf(var + EPS_);
}

// ---------------- K5: apply instance norm + ReLU ----------------
__global__ __launch_bounds__(256) void k5_norm(const float* __restrict__ pre,
                                               const float* __restrict__ stats,
                                               float* __restrict__ out) {
  const int i4 = blockIdx.x * 256 + threadIdx.x;
  const int plane = i4 / 9216;  // HW_/4 float4 per plane
  const float mu = stats[plane * 2];
  const float rs = stats[plane * 2 + 1];
  float4 v = ((const float4*)pre)[i4];
  v.x = fmaxf((v.x - mu) * rs, 0.f);
  v.y = fmaxf((v.y - mu) * rs, 0.f);
  v.z = fmaxf((v.z - mu) * rs, 0.f);
  v.w = fmaxf((v.w - mu) * rs, 0.f);
  ((float4*)out)[i4] = v;
}

extern "C" void kernel_launch(void* const* d_in, const int* in_sizes, int n_in,
                              void* d_out, int out_size, void* d_ws, size_t ws_size,
                              hipStream_t stream) {
  const float* x = (const float*)d_in[0];
  const float* dw_w = (const float*)d_in[1];
  const float* dw_b = (const float*)d_in[2];
  const float* bn_g = (const float*)d_in[3];
  const float* bn_b = (const float*)d_in[4];
  const float* bn_m = (const float*)d_in[5];
  const float* bn_v = (const float*)d_in[6];
  const float* pw_w = (const float*)d_in[7];
  const float* pw_b = (const float*)d_in[8];
  const float* dcn_w = (const float*)d_in[9];
  float* out = (float*)d_out;

  // workspace layout (floats)
  float* ws = (float*)d_ws;
  float* h = ws;                                  // B*C*HW = 4718592 (reused as pre)
  float* om = h + (size_t)B_ * C_ * HW_;          // B*27*HW = 1990656
  float* wT = om + (size_t)B_ * 27 * HW_;         // 9*64*64 = 36864
  float* pstats = wT + (size_t)K_ * C_ * O_;      // 512
  float* stats = pstats + 512;                    // 256
  if (ws_size < (size_t)(4718592 + 1990656 + 36864 + 512 + 256) * sizeof(float)) return;
  float* pre = h;  // h is dead after k2; reuse for pre-norm output

  k0_wt<<<dim3(144), dim3(256), 0, stream>>>(dcn_w, wT);
  k1_dw<<<dim3(HW_ / 256, B_ * C_), dim3(256), 0, stream>>>(x, dw_w, dw_b, bn_g, bn_b,
                                                            bn_m, bn_v, h);
  k2_pw<<<dim3(HW_ / 256, B_), dim3(256), 0, stream>>>(h, pw_w, pw_b, om);
  k3_dcn<<<dim3(B_ * HW_ / 64), dim3(256), 0, stream>>>(x, om, wT, pre);
  k4_part<<<dim3(B_ * O_ * 2), dim3(512), 0, stream>>>(pre, pstats);
  k4_fin<<<dim3(1), dim3(128), 0, stream>>>(pstats, stats);
  k5_norm<<<dim3(B_ * O_ * HW_ / 4 / 256), dim3(256), 0, stream>>>(pre, stats, out);
}

// Round 3
// 207.600 us; speedup vs baseline: 1.5741x; 1.0934x over previous
//
#include <hip/hip_runtime.h>
#include <math.h>

#define H_ 192
#define W_ 192
#define HW_ 36864
#define C_ 64
#define O_ 64
#define B_ 2
#define K_ 9
#define EPS_ 1e-5f

typedef __attribute__((ext_vector_type(8))) short short8;   // 8 bf16 = 4 VGPR
typedef __attribute__((ext_vector_type(4))) float f32x4;

__device__ __forceinline__ unsigned int f2bf(float f) {
  unsigned int u = __float_as_uint(f);
  u += 0x7FFFu + ((u >> 16) & 1u);   // RTN-even
  return u >> 16;
}
__device__ __forceinline__ unsigned int pk2bf(float lo, float hi) {
  return f2bf(lo) | (f2bf(hi) << 16);
}

// ---------------- K1: depthwise 3x3 conv + bias + BN + ReLU -> h ----------------
__global__ __launch_bounds__(256) void k1_dw(const float* __restrict__ x,
                                             const float* __restrict__ dw_w,
                                             const float* __restrict__ dw_b,
                                             const float* __restrict__ bn_g,
                                             const float* __restrict__ bn_b,
                                             const float* __restrict__ bn_m,
                                             const float* __restrict__ bn_v,
                                             float* __restrict__ h) {
  const int plane = blockIdx.y;                 // b*C + c
  const int c = plane & (C_ - 1);
  const int p = blockIdx.x * 256 + threadIdx.x;
  const int y = p / W_;
  const int xx = p - y * W_;
  const float* xp = x + (size_t)plane * HW_;
  float w[9];
#pragma unroll
  for (int i = 0; i < 9; ++i) w[i] = dw_w[c * 9 + i];
  float s = 0.f;
#pragma unroll
  for (int dy = 0; dy < 3; ++dy) {
    const int yy = y + dy - 1;
    if (yy < 0 || yy >= H_) continue;
#pragma unroll
    for (int dx = 0; dx < 3; ++dx) {
      const int xc = xx + dx - 1;
      if (xc < 0 || xc >= W_) continue;
      s = fmaf(w[dy * 3 + dx], xp[yy * W_ + xc], s);
    }
  }
  const float scale = bn_g[c] * rsqrtf(bn_v[c] + EPS_);
  const float shift = fmaf(dw_b[c] - bn_m[c], scale, bn_b[c]);
  h[(size_t)plane * HW_ + p] = fmaxf(fmaf(s, scale, shift), 0.f);
}

// ---------------- K2: pointwise 64->27 per pixel -> om ----------------
__global__ __launch_bounds__(256) void k2_pw(const float* __restrict__ h,
                                             const float* __restrict__ pw_w,
                                             const float* __restrict__ pw_b,
                                             float* __restrict__ om) {
  __shared__ float wl[C_ * 28];
  const int b = blockIdx.y;
  const int p = blockIdx.x * 256 + threadIdx.x;
  for (int i = threadIdx.x; i < C_ * 28; i += 256) {
    const int c = i / 28, j = i - c * 28;
    wl[i] = (j < 27) ? pw_w[j * C_ + c] : 0.f;
  }
  __syncthreads();
  float s[27];
#pragma unroll
  for (int j = 0; j < 27; ++j) s[j] = 0.f;
  const float* hp = h + (size_t)b * C_ * HW_ + p;
  for (int c = 0; c < C_; ++c) {
    const float hv = hp[(size_t)c * HW_];
    float wv[28];
#pragma unroll
    for (int q = 0; q < 7; ++q)
      *(float4*)&wv[q * 4] = *(const float4*)&wl[c * 28 + q * 4];
#pragma unroll
    for (int j = 0; j < 27; ++j) s[j] = fmaf(hv, wv[j], s[j]);
  }
  float* op = om + (size_t)b * 27 * HW_ + p;
#pragma unroll
  for (int j = 0; j < 27; ++j) op[(size_t)j * HW_] = s[j] + pw_b[j];
}

// ---------------- K0: dcn_w (O,C,3,3) fp32 -> wT2[k][o][c] bf16 ----------------
__global__ __launch_bounds__(256) void k0_wt(const float* __restrict__ dcn_w,
                                             unsigned short* __restrict__ wT2) {
  const int i = blockIdx.x * 256 + threadIdx.x;  // (o*C + c)*9 + k
  const int o = i / (C_ * 9);
  const int rem = i - o * (C_ * 9);
  const int c = rem / 9;
  const int kk = rem - c * 9;
  wT2[((size_t)(kk * O_) + o) * C_ + c] = (unsigned short)f2bf(dcn_w[i]);
}

// ---------------- K3: fused deformable gather (fp32) + MFMA bf16 contraction ----
// 64-px tile, 64 o, 256 threads (4 waves). Wave w owns o-strip [w*16, w*16+16).
// LDS tiles [row][64c] bf16, XOR-swizzled 16B blocks (blk ^= row&7) -> no 16-way conflicts.
__global__ __launch_bounds__(256, 4) void k3_dcn(const float* __restrict__ x,
                                                 const float* __restrict__ om,
                                                 const unsigned short* __restrict__ wT2,
                                                 float* __restrict__ pre) {
  __shared__ __align__(16) unsigned short wlds[4096];  // [o][c] bf16 swz, 8 KB
  __shared__ __align__(16) unsigned short vlds[4096];  // [px][c] bf16 swz, 8 KB

  const int tid = threadIdx.x;
  // bijective XCD swizzle: 1152 blocks = 8 XCD x 144 contiguous tiles
  const int t = (blockIdx.x & 7) * 144 + (blockIdx.x >> 3);
  const int b = t / 576;
  const int p0 = (t - b * 576) * 64;
  const float* xb = x + (size_t)b * C_ * HW_;
  const float* omb = om + (size_t)b * 27 * HW_;

  const int pxi = tid & 63;   // gather pixel
  const int cq = tid >> 6;    // wave id == channel-quarter for gather == o-strip/16
  const int lr = pxi & 15;    // lane&15
  const int lg = pxi >> 4;    // lane>>4 (k-group)
  const int oo0 = cq * 16;

  const int p = p0 + pxi;
  const int y = p / W_;
  const int xx = p - y * W_;

  f32x4 acc[4];
#pragma unroll
  for (int j = 0; j < 4; ++j) acc[j] = (f32x4){0.f, 0.f, 0.f, 0.f};

  for (int k = 0; k < K_; ++k) {
    // --- issue w-stage loads early (L2-resident, 2 x 16B per thread)
    const uint4* wsrc = (const uint4*)(wT2 + (k << 12));
    const uint4 wv0 = wsrc[tid];
    const uint4 wv1 = wsrc[tid + 256];
    // --- bilinear coords for this tap (per-thread, redundant x4 per px)
    const float dyv = omb[(size_t)(2 * k) * HW_ + p];
    const float dxv = omb[(size_t)(2 * k + 1) * HW_ + p];
    float mk = omb[(size_t)(18 + k) * HW_ + p];
    mk = 1.f / (1.f + __expf(-mk));
    const int ky = k / 3;
    const int kx = k - ky * 3;
    const float py = (float)(y + ky - 1) + dyv;
    const float pxf = (float)(xx + kx - 1) + dxv;
    const float y0f = floorf(py), x0f = floorf(pxf);
    const float wy1 = py - y0f, wx1 = pxf - x0f;
    const float wy0 = 1.f - wy1, wx0 = 1.f - wx1;
    const int y0 = (int)y0f, x0i = (int)x0f;
    const int y1 = y0 + 1, x1i = x0i + 1;
    const bool vy0 = (y0 >= 0) & (y0 < H_);
    const bool vy1 = (y1 >= 0) & (y1 < H_);
    const bool vx0 = (x0i >= 0) & (x0i < W_);
    const bool vx1 = (x1i >= 0) & (x1i < W_);
    const int yc0 = min(max(y0, 0), H_ - 1), yc1 = min(max(y1, 0), H_ - 1);
    const int xc0 = min(max(x0i, 0), W_ - 1), xc1 = min(max(x1i, 0), W_ - 1);
    const int i0 = yc0 * W_ + xc0, i1 = yc0 * W_ + xc1;
    const int i2 = yc1 * W_ + xc0, i3 = yc1 * W_ + xc1;
    const float g0 = (vy0 & vx0) ? wy0 * wx0 * mk : 0.f;
    const float g1 = (vy0 & vx1) ? wy0 * wx1 * mk : 0.f;
    const float g2 = (vy1 & vx0) ? wy1 * wx0 * mk : 0.f;
    const float g3 = (vy1 & vx1) ? wy1 * wx1 * mk : 0.f;

    // --- gather 16 channels (c = cq*8+i and +32) into regs, before barrier
    float val[16];
#pragma unroll
    for (int i = 0; i < 8; ++i) {
      const int c = (cq << 3) + i;
      const float* pl = xb + (size_t)c * HW_;
      val[i] = fmaf(g0, pl[i0], fmaf(g1, pl[i1], fmaf(g2, pl[i2], g3 * pl[i3])));
      const float* ph = pl + 32 * HW_;
      val[8 + i] = fmaf(g0, ph[i0], fmaf(g1, ph[i1], fmaf(g2, ph[i2], g3 * ph[i3])));
    }

    __syncthreads();  // (A) all waves done MFMA-reading previous tap's LDS
    // --- stage w tap (swizzled 16B blocks): block index i -> row i>>3, blk i&7
    {
      const int r0 = tid >> 3, b0 = tid & 7;
      ((uint4*)wlds)[(r0 << 3) + (b0 ^ (r0 & 7))] = wv0;
      const int r1 = (tid + 256) >> 3;
      ((uint4*)wlds)[(r1 << 3) + (b0 ^ (r1 & 7))] = wv1;
    }
    // --- pack gathered vals to bf16 and write vlds rows (swizzled)
    {
      uint4 pka, pkb;
      pka.x = pk2bf(val[0], val[1]);
      pka.y = pk2bf(val[2], val[3]);
      pka.z = pk2bf(val[4], val[5]);
      pka.w = pk2bf(val[6], val[7]);
      pkb.x = pk2bf(val[8], val[9]);
      pkb.y = pk2bf(val[10], val[11]);
      pkb.z = pk2bf(val[12], val[13]);
      pkb.w = pk2bf(val[14], val[15]);
      const int rsw = pxi & 7;
      ((uint4*)vlds)[(pxi << 3) + (cq ^ rsw)] = pka;
      ((uint4*)vlds)[(pxi << 3) + ((cq + 4) ^ rsw)] = pkb;
    }
    __syncthreads();  // (B) wlds + vlds ready
    // --- MFMA: D[o-strip 16][px 64] += w[o][c] * val[c][px], K=64 in 2 steps
#pragma unroll
    for (int ks = 0; ks < 2; ++ks) {
      const int kb = (ks << 2) + lg;  // 16B block (8 bf16 of k) within row
      const int ra = oo0 + lr;
      const short8 afr = *(const short8*)&((const uint4*)wlds)[(ra << 3) + (kb ^ (ra & 7))];
#pragma unroll
      for (int j = 0; j < 4; ++j) {
        const int rb = (j << 4) + lr;
        const short8 bfr = *(const short8*)&((const uint4*)vlds)[(rb << 3) + (kb ^ (rb & 7))];
        acc[j] = __builtin_amdgcn_mfma_f32_16x16x32_bf16(afr, bfr, acc[j], 0, 0, 0);
      }
    }
  }
  // --- store: D col = lane&15 (px), row = lg*4 + q (o). dcn_b cancels in IN.
  float* outb = pre + ((size_t)b * O_ + oo0 + (lg << 2)) * HW_ + p0;
#pragma unroll
  for (int j = 0; j < 4; ++j)
#pragma unroll
    for (int q = 0; q < 4; ++q)
      outb[(size_t)q * HW_ + (j << 4) + lr] = acc[j][q];
}

// ---------------- K4: instance-norm stats (two-pass, deterministic) ----------------
__global__ __launch_bounds__(512) void k4_part(const float* __restrict__ pre,
                                               float* __restrict__ pstats) {
  const int plane = blockIdx.x >> 1;
  const int half = blockIdx.x & 1;
  const float4* p4 = (const float4*)(pre + (size_t)plane * HW_) + half * 4608;
  float s = 0.f, s2 = 0.f;
#pragma unroll
  for (int q = 0; q < 9; ++q) {
    const float4 v = p4[q * 512 + threadIdx.x];
    s += v.x + v.y + v.z + v.w;
    s2 = fmaf(v.x, v.x, s2);
    s2 = fmaf(v.y, v.y, s2);
    s2 = fmaf(v.z, v.z, s2);
    s2 = fmaf(v.w, v.w, s2);
  }
#pragma unroll
  for (int off = 32; off > 0; off >>= 1) {
    s += __shfl_down(s, off);
    s2 += __shfl_down(s2, off);
  }
  __shared__ float ls[8], ls2[8];
  const int wid = threadIdx.x >> 6, lane = threadIdx.x & 63;
  if (lane == 0) { ls[wid] = s; ls2[wid] = s2; }
  __syncthreads();
  if (threadIdx.x == 0) {
    float ts = 0.f, ts2 = 0.f;
#pragma unroll
    for (int w = 0; w < 8; ++w) { ts += ls[w]; ts2 += ls2[w]; }
    pstats[blockIdx.x * 2] = ts;
    pstats[blockIdx.x * 2 + 1] = ts2;
  }
}

__global__ void k4_fin(const float* __restrict__ pstats, float* __restrict__ stats) {
  const int p = threadIdx.x;  // 0..127 = b*O + o
  const float s = pstats[(2 * p) * 2] + pstats[(2 * p + 1) * 2];
  const float s2 = pstats[(2 * p) * 2 + 1] + pstats[(2 * p + 1) * 2 + 1];
  const float inv = 1.f / (float)HW_;
  const float mu = s * inv;
  const float var = fmaxf(fmaf(-mu, mu, s2 * inv), 0.f);
  stats[p * 2] = mu;
  stats[p * 2 + 1] = rsqrtf(var + EPS_);
}

// ---------------- K5: apply instance norm + ReLU ----------------
__global__ __launch_bounds__(256) void k5_norm(const float* __restrict__ pre,
                                               const float* __restrict__ stats,
                                               float* __restrict__ out) {
  const int i4 = blockIdx.x * 256 + threadIdx.x;
  const int plane = i4 / 9216;
  const float mu = stats[plane * 2];
  const float rs = stats[plane * 2 + 1];
  float4 v = ((const float4*)pre)[i4];
  v.x = fmaxf((v.x - mu) * rs, 0.f);
  v.y = fmaxf((v.y - mu) * rs, 0.f);
  v.z = fmaxf((v.z - mu) * rs, 0.f);
  v.w = fmaxf((v.w - mu) * rs, 0.f);
  ((float4*)out)[i4] = v;
}

extern "C" void kernel_launch(void* const* d_in, const int* in_sizes, int n_in,
                              void* d_out, int out_size, void* d_ws, size_t ws_size,
                              hipStream_t stream) {
  const float* x = (const float*)d_in[0];
  const float* dw_w = (const float*)d_in[1];
  const float* dw_b = (const float*)d_in[2];
  const float* bn_g = (const float*)d_in[3];
  const float* bn_b = (const float*)d_in[4];
  const float* bn_m = (const float*)d_in[5];
  const float* bn_v = (const float*)d_in[6];
  const float* pw_w = (const float*)d_in[7];
  const float* pw_b = (const float*)d_in[8];
  const float* dcn_w = (const float*)d_in[9];
  float* out = (float*)d_out;

  // workspace layout (floats)
  float* ws = (float*)d_ws;
  float* h = ws;                                  // B*C*HW = 4718592 (reused as pre)
  float* om = h + (size_t)B_ * C_ * HW_;          // B*27*HW = 1990656
  unsigned short* wT2 = (unsigned short*)(om + (size_t)B_ * 27 * HW_);  // 36864 u16
  float* pstats = (float*)(wT2 + (size_t)K_ * O_ * C_);  // 512
  float* stats = pstats + 512;                    // 256
  if (ws_size < (size_t)(4718592 + 1990656 + 18432 + 512 + 256) * sizeof(float)) return;
  float* pre = h;  // h is dead after k2; reuse for pre-norm output

  k0_wt<<<dim3(144), dim3(256), 0, stream>>>(dcn_w, wT2);
  k1_dw<<<dim3(HW_ / 256, B_ * C_), dim3(256), 0, stream>>>(x, dw_w, dw_b, bn_g, bn_b,
                                                            bn_m, bn_v, h);
  k2_pw<<<dim3(HW_ / 256, B_), dim3(256), 0, stream>>>(h, pw_w, pw_b, om);
  k3_dcn<<<dim3(B_ * HW_ / 64), dim3(256), 0, stream>>>(x, om, wT2, pre);
  k4_part<<<dim3(B_ * O_ * 2), dim3(512), 0, stream>>>(pre, pstats);
  k4_fin<<<dim3(1), dim3(128), 0, stream>>>(pstats, stats);
  k5_norm<<<dim3(B_ * O_ * HW_ / 4 / 256), dim3(256), 0, stream>>>(pre, stats, out);
}